// Round 3
// baseline (775.677 us; speedup 1.0000x reference)
//
#include <hip/hip_runtime.h>
#include <math.h>

#define Bb 8
#define Cc 64
#define Hh 256
#define Ww 256
#define HID 8
#define PLANE (Hh*Ww)

// ---------------- theta kernel: LDS-tiled 3x3 conv -> 1x1 -> sigmoid*pi ----
// Block = 64x4 pixels. Tile per channel: 6 x 66 (zero-padded at image
// borders). 8 channels staged per barrier phase; staging addresses hoisted.
#define T2H 6
#define T2W 66
#define T2P 67
#define T2SZ (T2H*T2P)   // 402 dwords
#define TBATCH 8

__global__ __launch_bounds__(256) void theta_kernel(
    const float* __restrict__ x, const float* __restrict__ w3,
    const float* __restrict__ b3, const float* __restrict__ w1,
    const float* __restrict__ b1, float* __restrict__ cosout,
    float* __restrict__ sinout)
{
    __shared__ float tile[TBATCH * T2SZ];   // 12.9 KB
    const int tid = threadIdx.x;
    const int tx = tid & 63;
    const int ty = tid >> 6;
    const int xx = blockIdx.x * 64 + tx;
    const int yy = blockIdx.y * 4 + ty;
    const int b  = blockIdx.z;
    const int row0 = blockIdx.y * 4 - 1;
    const int col0 = blockIdx.x * 64 - 1;

    // Hoisted staging descriptors: element e = tid + 256*j of the 6x66 tile.
    // Slot 0 always valid (256 < 396); slot 1 valid iff tid < 140.
    int goff0, laddr0, goff1 = 0, laddr1 = 0;
    bool inb0, inb1 = false;
    {
        const int e = tid;
        const int r = e / T2W, cc = e - r * T2W;
        const int gy = row0 + r, gx = col0 + cc;
        inb0 = (gy >= 0 && gy < Hh && gx >= 0 && gx < Ww);
        goff0 = gy * Ww + gx;
        laddr0 = r * T2P + cc;
    }
    const bool slot1 = (tid < T2H * T2W - 256);
    if (slot1) {
        const int e = tid + 256;
        const int r = e / T2W, cc = e - r * T2W;
        const int gy = row0 + r, gx = col0 + cc;
        inb1 = (gy >= 0 && gy < Hh && gx >= 0 && gx < Ww);
        goff1 = gy * Ww + gx;
        laddr1 = r * T2P + cc;
    }

    const float* xb = x + (size_t)b * Cc * PLANE;

    float acc[HID];
    #pragma unroll
    for (int h = 0; h < HID; h++) acc[h] = 0.f;

    const int lbase = (ty + 1) * T2P + (tx + 1);  // local center

    for (int cb = 0; cb < Cc; cb += TBATCH) {
        __syncthreads();
        #pragma unroll
        for (int k = 0; k < TBATCH; k++) {
            const float* xc = xb + (size_t)(cb + k) * PLANE;
            float v0 = 0.f;
            if (inb0) v0 = xc[goff0];
            tile[k * T2SZ + laddr0] = v0;
            if (slot1) {
                float v1 = 0.f;
                if (inb1) v1 = xc[goff1];
                tile[k * T2SZ + laddr1] = v1;
            }
        }
        __syncthreads();
        #pragma unroll
        for (int k = 0; k < TBATCH; k++) {
            const float* tp = &tile[k * T2SZ];
            float v[9];
            #pragma unroll
            for (int dy = 0; dy < 3; dy++)
                #pragma unroll
                for (int dx = 0; dx < 3; dx++)
                    v[dy * 3 + dx] = tp[lbase + (dy - 1) * T2P + (dx - 1)];
            const int c = cb + k;
            #pragma unroll
            for (int h = 0; h < HID; h++) {
                const float* wk = w3 + (h * Cc + c) * 9;  // uniform -> s_load
                float a = acc[h];
                #pragma unroll
                for (int kk = 0; kk < 9; kk++) a = fmaf(wk[kk], v[kk], a);
                acc[h] = a;
            }
        }
    }

    float z = b1[0];
    #pragma unroll
    for (int h = 0; h < HID; h++) {
        float hr = acc[h] + b3[h];
        hr = hr > 0.f ? hr : 0.f;
        z = fmaf(w1[h], hr, z);
    }
    const float theta = 3.14159265358979f / (1.f + __expf(-z));
    float s, co;
    __sincosf(theta, &s, &co);
    const int p = b * PLANE + yy * Ww + xx;
    cosout[p] = co;
    sinout[p] = s;
}

// ---------------- pool kernel: LDS-tiled oriented pooling + attention -------
// Block = 64x4 pixels; per-channel footprint 13 x 74 (all 18 bilinear taps,
// |t|<=4, +1 neighbors). 4 channels staged per barrier phase; staging
// addresses hoisted out of the channel loop.
#define TPH 13
#define TPW 74
#define TPP 75   // odd stride, gcd(75,32)=1
#define TSZ (TPH*TPP)   // 975 dwords
#define PB 4

__global__ __launch_bounds__(256) void pool_kernel(
    const float* __restrict__ x,
    const float* __restrict__ cosb, const float* __restrict__ sinb,
    const float* __restrict__ wr, const float* __restrict__ br,
    const float* __restrict__ we, const float* __restrict__ be,
    float* __restrict__ out)
{
    __shared__ float tile[PB * TSZ];   // 15.6 KB
    const int tid = threadIdx.x;
    const int tx = tid & 63;
    const int ty = tid >> 6;
    const int xx = blockIdx.x * 64 + tx;
    const int yy = blockIdx.y * 4 + ty;
    const int b  = blockIdx.z;
    const int p  = b * PLANE + yy * Ww + xx;
    const int row0 = blockIdx.y * 4 - 4;
    const int col0 = blockIdx.x * 64 - 4;

    const float vx = cosb[p];   // cos(theta)
    const float vy = sinb[p];   // sin(theta)

    // Hoisted staging descriptors: 962 elements, 4 slots/thread.
    // Slots 0-2 always valid; slot 3 valid iff tid < 194.
    int goff[4], laddr[4];
    #pragma unroll
    for (int j = 0; j < 4; j++) {
        const int e = tid + 256 * j;
        int r = e / TPW, cc = e - r * TPW;
        if (e >= TPH * TPW) { r = 0; cc = 0; }
        const int gy = min(max(row0 + r, 0), Hh - 1);
        const int gx = min(max(col0 + cc, 0), Ww - 1);
        goff[j] = gy * Ww + gx;
        laddr[j] = r * TPP + cc;
    }
    const bool slot3 = (tid < TPH * TPW - 768);

    // 18 bilinear descriptors with tile-local dword offsets.
    // Clamp trick: x0=min(floor(cx),W-2), wx=cx-x0 == reference edge behavior.
    int   off[18];
    float fwy[18], fwx[18];
    #pragma unroll
    for (int s = 0; s < 9; s++) {
        const float t = (float)(s - 4);
        float cy = fminf(fmaxf((float)yy + t * vy, 0.f), (float)(Hh - 1));
        float cx = fminf(fmaxf((float)xx + t * vx, 0.f), (float)(Ww - 1));
        int y0 = min((int)cy, Hh - 2);
        int x0 = min((int)cx, Ww - 2);
        off[s] = (y0 - row0) * TPP + (x0 - col0);
        fwy[s] = cy - (float)y0;
        fwx[s] = cx - (float)x0;
        float cy2 = fminf(fmaxf((float)yy + t * vx, 0.f), (float)(Hh - 1));
        float cx2 = fminf(fmaxf((float)xx - t * vy, 0.f), (float)(Ww - 1));
        int y02 = min((int)cy2, Hh - 2);
        int x02 = min((int)cx2, Ww - 2);
        off[9 + s] = (y02 - row0) * TPP + (x02 - col0);
        fwy[9 + s] = cy2 - (float)y02;
        fwx[9 + s] = cx2 - (float)x02;
    }

    float hid[HID];
    #pragma unroll
    for (int h = 0; h < HID; h++) hid[h] = br[h];

    const float* xb = x + (size_t)b * Cc * PLANE;

    for (int cb = 0; cb < Cc; cb += PB) {
        __syncthreads();
        #pragma unroll
        for (int k = 0; k < PB; k++) {
            const float* xc = xb + (size_t)(cb + k) * PLANE;
            tile[k * TSZ + laddr[0]] = xc[goff[0]];
            tile[k * TSZ + laddr[1]] = xc[goff[1]];
            tile[k * TSZ + laddr[2]] = xc[goff[2]];
            if (slot3) tile[k * TSZ + laddr[3]] = xc[goff[3]];
        }
        __syncthreads();
        #pragma unroll
        for (int k = 0; k < PB; k++) {
            const float* tp = &tile[k * TSZ];
            float tacc = 0.f, nacc = 0.f;
            #pragma unroll
            for (int s = 0; s < 18; s++) {
                const int o = off[s];
                const float v00 = tp[o];
                const float v01 = tp[o + 1];         // ds_read2 with v00
                const float v10 = tp[o + TPP];
                const float v11 = tp[o + TPP + 1];   // ds_read2 with v10
                const float wx_ = fwx[s], wy_ = fwy[s];
                const float top = v00 + wx_ * (v01 - v00);
                const float bot = v10 + wx_ * (v11 - v10);
                const float val = top + wy_ * (bot - top);
                if (s < 9) tacc += val; else nacc += val;
            }
            tacc *= (1.f / 9.f);
            nacc *= (1.f / 9.f);
            const int c = cb + k;
            #pragma unroll
            for (int h = 0; h < HID; h++) {
                hid[h] = fmaf(wr[h * 128 + c],      tacc, hid[h]);  // uniform
                hid[h] = fmaf(wr[h * 128 + 64 + c], nacc, hid[h]);
            }
        }
    }

    #pragma unroll
    for (int h = 0; h < HID; h++) hid[h] = fmaxf(hid[h], 0.f);

    // Epilogue: w = sigmoid(we @ hidden + be); out = (w[c] + w[c+64]) * x[c]
    const int pix = yy * Ww + xx;
    for (int c = 0; c < Cc; c++) {
        float z1 = be[c];
        float z2 = be[c + 64];
        #pragma unroll
        for (int h = 0; h < HID; h++) {
            z1 = fmaf(we[c * 8 + h],        hid[h], z1);
            z2 = fmaf(we[(c + 64) * 8 + h], hid[h], z2);
        }
        const float a1 = 1.f / (1.f + __expf(-z1));
        const float a2 = 1.f / (1.f + __expf(-z2));
        const float xv = xb[c * PLANE + pix];
        out[(size_t)(b * Cc + c) * PLANE + pix] = (a1 + a2) * xv;
    }
}

extern "C" void kernel_launch(void* const* d_in, const int* in_sizes, int n_in,
                              void* d_out, int out_size, void* d_ws, size_t ws_size,
                              hipStream_t stream) {
    const float* x  = (const float*)d_in[0];
    const float* w3 = (const float*)d_in[1];
    const float* b3 = (const float*)d_in[2];
    const float* w1 = (const float*)d_in[3];
    const float* b1 = (const float*)d_in[4];
    const float* wr = (const float*)d_in[5];
    const float* br = (const float*)d_in[6];
    const float* we = (const float*)d_in[7];
    const float* be = (const float*)d_in[8];
    float* out = (float*)d_out;

    float* cosb = (float*)d_ws;                    // B*H*W floats
    float* sinb = cosb + (size_t)Bb * PLANE;       // B*H*W floats

    dim3 grid(Ww / 64, Hh / 4, Bb);
    dim3 block(256);
    theta_kernel<<<grid, block, 0, stream>>>(x, w3, b3, w1, b1, cosb, sinb);
    pool_kernel<<<grid, block, 0, stream>>>(x, cosb, sinb, wr, br, we, be, out);
}